// Round 9
// baseline (196.145 us; speedup 1.0000x reference)
//
#include <hip/hip_runtime.h>

typedef _Float16 h8 __attribute__((ext_vector_type(8)));
typedef _Float16 h4 __attribute__((ext_vector_type(4)));
typedef float f32x4 __attribute__((ext_vector_type(4)));
typedef float f32x16 __attribute__((ext_vector_type(16)));
typedef unsigned int u32x4 __attribute__((ext_vector_type(4)));

union HU { _Float16 h; unsigned short u; };
__device__ __forceinline__ unsigned short f2h(float f) { HU x; x.h = (_Float16)f; return x.u; }
__device__ __forceinline__ float h2f(unsigned short u) { HU x; x.u = u; return (float)x.h; }

#define MFMA16(a, b, c) __builtin_amdgcn_mfma_f32_16x16x32_f16((a), (b), (c), 0, 0, 0)
#define MFMA32(a, b, c) __builtin_amdgcn_mfma_f32_32x32x16_f16((a), (b), (c), 0, 0, 0)

// ---------------------------------------------------------------------------
// k_prep: identical to rounds 12-17 (w2f packed for 32x32x16 MFMA: per tap t,
// 64 lanes x h8, n = lane&31 (oc), k = (lane>>5)*8+j (ic)). Validated.
// ---------------------------------------------------------------------------
__global__ void k_prep(const float* __restrict__ w1, const float* __restrict__ w2,
                       const float* __restrict__ w3,
                       const float* __restrict__ ptw1, const float* __restrict__ cfw1,
                       const float* __restrict__ ptw2, const float* __restrict__ ptw3,
                       const float* __restrict__ cfw2,
                       unsigned short* __restrict__ w1f,
                       unsigned short* __restrict__ w2f,
                       unsigned short* __restrict__ w3f,
                       unsigned short* __restrict__ w1hd,
                       unsigned short* __restrict__ w2hd,
                       unsigned short* __restrict__ w3hd) {
    int gid = blockIdx.x * 256 + threadIdx.x;
    int gs = gridDim.x * 256;
    for (int e = gid; e < 1024; e += gs) {
        int f = e >> 9, lane = (e >> 3) & 63, j = e & 7;
        int k = ((lane >> 4) << 3) + j, oc = lane & 15;
        int r, within;
        if (f == 0) { r = k >> 4; within = k & 15; }
        else        { r = 2;      within = k; }
        int tx = within >> 2, ch = within & 3;
        float v = 0.f;
        if (tx < 3 && ch < 3) v = w1[oc * 27 + ch * 9 + r * 3 + tx];
        w1f[e] = f2h(v);
    }
    for (int e = gid; e < 4608; e += gs) {
        int j = e & 7, lane = (e >> 3) & 63, t = e >> 9;
        int oc = lane & 31, k = ((lane >> 5) << 3) + j;
        w2f[e] = f2h(w2[oc * 144 + k * 9 + t]);
    }
    for (int e = gid; e < 18432; e += gs) {
        int j = e & 7, lane = (e >> 3) & 63, fo = e >> 9;
        int oti = fo & 1, t = (fo >> 1) % 9, otp = (fo >> 1) / 9;
        int ic = ((lane >> 4) * 8) + j, oc = (otp * 2 + oti) * 16 + (lane & 15);
        w3f[e] = f2h(w3[oc * 288 + ic * 9 + t]);
    }
    for (int s = gid; s < 608 * 192; s += gs) {
        int k = s / 192, n = s - k * 192;
        float v = 0.f;
        if (k < 584) {
            int f = (k < 576) ? ((k & 63) * 9 + (k >> 6)) : k;
            v = (n < 128) ? ptw1[f * 128 + n] : cfw1[f * 64 + (n - 128)];
        }
        int kk = k >> 5, hi = (k & 31) >> 3, j = k & 7, nt = n >> 4;
        int e = (((kk * 12 + nt) << 6) | (hi << 4) | (n & 15)) << 3 | j;
        w1hd[e] = f2h(v);
    }
    for (int s = gid; s < 8192; s += gs) {
        int k = s >> 6, n = s & 63;
        float v = ptw2[k * 64 + n];
        int kk = k >> 5, hi = (k & 31) >> 3, j = k & 7, nt = n >> 4;
        int e = ((((kk << 2) | nt) << 6) | (hi << 4) | (n & 15)) << 3 | j;
        w2hd[e] = f2h(v);
    }
    for (int e = gid; e < 2048; e += gs) {
        int j = e & 7, lane = (e >> 3) & 63, kk = e >> 9;
        int k = kk * 32 + ((lane >> 4) * 8) + j, n = lane & 15;
        float v = 0.f;
        if (k < 64) { if (n < 2) v = ptw3[k * 2 + n]; }
        else        { if (n == 2) v = cfw2[k - 64]; }
        w3hd[e] = f2h(v);
    }
}

// ---------------------------------------------------------------------------
// k_fused, round 21: 2-WAVE blocks (128 thr, 16 samples). LDS 28032 B ->
// 5 independent blocks/CU (vs 3), barrier groups of 2 waves (vs 4),
// 8 barriers (vs 10). conv2 on 32x32x16 via r14's validated half-fold
// (M = 32 = x-half*16 + sample), legal here because __launch_bounds__(128,2)
// gives a 256-reg cap (the (256,3) ~170 cap caused r15/r17 spills).
// LDS map (halfs): [0,9856) A1/A2/FT/ZS/L2out overlay region;
//                  [9856,14016) BD -> Hb(3200)+O(128).
// ---------------------------------------------------------------------------
#define BDS4 260
#define A1S 584
#define A2S 296
#define FTS 616
#define HSH 200
#define ZSH 9344
#define RA_OFF 9856
#define O_OFF 13056
#define LDSTOT 14016

__device__ __forceinline__ u32x4 conv2_cell(const unsigned short* __restrict__ Ab,
                                            const unsigned short* __restrict__ Zp,
                                            const h8 (&W2r)[9], float b2v,
                                            int pr, int pc, int half) {
    f32x16 pool;
    #pragma unroll
    for (int r = 0; r < 16; r++) pool[r] = 0.f;
    #pragma unroll
    for (int sy = 0; sy < 2; sy++) {
        const int oy = pr * 2 + sy;
        f32x16 acc;
        #pragma unroll
        for (int r = 0; r < 16; r++) acc[r] = 0.f;
        #pragma unroll
        for (int dy = -1; dy <= 1; dy++) {
            const int ys = oy + dy;
            if (ys < 0 || ys > 5) continue;
            #pragma unroll
            for (int dx = -1; dx <= 1; dx++) {
                const int xc = pc * 2 + half + dx;
                const unsigned short* ap =
                    (xc < 0 || xc > 5) ? Zp : &Ab[(ys * 6 + xc) * 16];
                h8 a = *(const h8*)ap;
                acc = MFMA32(a, W2r[(dy + 1) * 3 + (dx + 1)], acc);
            }
        }
        #pragma unroll
        for (int r = 0; r < 16; r++)
            pool[r] = fmaxf(pool[r], acc[r] + b2v);   // relu via 0-init
    }
    // fold x-halves (rows r and r+16 == regs r and r+8), pack to halfs
    u32x4 pk;
    #pragma unroll
    for (int i = 0; i < 4; i++) {
        float v0 = fmaxf(pool[2 * i], pool[2 * i + 8]);
        float v1 = fmaxf(pool[2 * i + 1], pool[2 * i + 9]);
        pk[i] = (unsigned)f2h(v0) | ((unsigned)f2h(v1) << 16);
    }
    return pk;
}

__global__ __launch_bounds__(128, 2) void k_fused(
    const float* __restrict__ board,
    const float* __restrict__ b1, const float* __restrict__ b2,
    const float* __restrict__ b3, const float* __restrict__ qp,
    const unsigned short* __restrict__ w1f,
    const unsigned short* __restrict__ w2f,
    const unsigned short* __restrict__ w3f,
    const unsigned short* __restrict__ w1hd,
    const unsigned short* __restrict__ w2hd,
    const unsigned short* __restrict__ w3hd,
    const float* __restrict__ ptb1, const float* __restrict__ ptb2,
    const float* __restrict__ ptb3, const float* __restrict__ cfb1,
    const float* __restrict__ cfb2,
    float* __restrict__ out)
{
    __shared__ __align__(16) unsigned short LDSH[LDSTOT];
    const int tid = threadIdx.x, wid = tid >> 6, lane = tid & 63;
    const int col = lane & 15, q = lane >> 4;
    const long long gg0 = (long long)blockIdx.x * 16;
    const f32x4 ZERO4 = {0.f, 0.f, 0.f, 0.f};

    unsigned short* Hb = LDSH + RA_OFF;     // overlays BD (dead after conv1)
    float* O = (float*)(LDSH + O_OFF);

    // ---- 0. issue board preloads + quantum global loads ----
    const f32x4* bp4 = (const f32x4*)(board + gg0 * 108);
    f32x4 v0 = bp4[tid];
    f32x4 v1 = bp4[tid + 128];
    f32x4 v2 = bp4[tid + 256];
    f32x4 v3 = ZERO4;
    if (tid < 48) v3 = bp4[tid + 384];

    float xq0, xn0;
    {
        int ss = tid >> 3, qq = tid & 7, e2 = (qq + 1) & 7;
        const float* b0p = board + (gg0 + ss) * 108;
        xq0 = b0p[qq];  xn0 = b0p[e2];
    }

    // ---- 1. stage board + zero halo/ch3/spare + zero conv2 slab ----
    {
        {   // zero: per (sample ss = tid>>3, row = tid&7)
            int ss = tid >> 3, row = tid & 7;
            unsigned long long* Z =
                (unsigned long long*)&LDSH[RA_OFF + ss * BDS4];
            if (row == 0) {
                #pragma unroll
                for (int i = 0; i < 8; i++) Z[i] = 0ULL;
            } else if (row == 7) {
                #pragma unroll
                for (int i = 56; i < 65; i++) Z[i] = 0ULL;   // row 7 + spares
            } else {
                Z[row * 8] = 0ULL;
                Z[row * 8 + 7] = 0ULL;
                #pragma unroll
                for (int c = 1; c < 7; c++)
                    LDSH[RA_OFF + ss * BDS4 + row * 32 + c * 4 + 3] = 0;
            }
        }
        if (tid < 4) ((unsigned long long*)&LDSH[ZSH])[tid] = 0ULL;
        // unpack 432 f32x4 over 128 threads (3 full + partial 4th)
        #pragma unroll
        for (int blk = 0; blk < 4; blk++) {
            if (blk == 3 && tid >= 48) break;
            f32x4 v = (blk == 0) ? v0 : (blk == 1) ? v1 : (blk == 2) ? v2 : v3;
            int e4 = tid + blk * 128;
            int ss = e4 / 27, r27 = e4 - ss * 27, f0 = r27 * 4;
            #pragma unroll
            for (int j = 0; j < 4; j++) {
                int f = f0 + j, ch = f / 36, p = f - ch * 36;
                LDSH[RA_OFF + ss * BDS4 + ((p / 6 + 1) * 8 + (p % 6) + 1) * 4 + ch] =
                    f2h(v[j]);
            }
        }
    }
    __syncthreads();

    // ---- 2. conv1 (18 pos/wave) + quantum VALU chain (overlaps MFMA) ----
    float qv0;
    {
        int qq = tid & 7;
        float s0 = 0.f;
        for (int l = 0; l < 3; l++) {
            float a0 = qp[l * 24 + qq * 3], a1 = qp[l * 24 + qq * 3 + 1],
                  a2 = qp[l * 24 + qq * 3 + 2];
            s0 = sinf(a0 * xq0) * cosf(a1 * xn0) + tanhf(a2 * s0);
        }
        qv0 = s0;
    }
    {
        h8 w1r0 = ((const h8*)w1f)[lane];
        h8 w1r1 = ((const h8*)w1f)[64 + lane];
        float b1v = b1[col];
        const int bs = RA_OFF + col * BDS4;
        const int rsel = q >> 1, wo = (q & 1) * 8;
        for (int p = wid * 18; p < wid * 18 + 18; p++) {
            int y = p / 6, x = p % 6;
            int ab1 = bs + ((y + rsel) * 8 + x) * 4 + wo;
            int ab2 = bs + ((y + 2) * 8 + x) * 4 + wo;
            union { h8 v; h4 h[2]; } a1v, a2v;
            a1v.h[0] = *(const h4*)&LDSH[ab1];
            a1v.h[1] = *(const h4*)&LDSH[ab1 + 4];
            a2v.h[0] = *(const h4*)&LDSH[ab2];
            a2v.h[1] = *(const h4*)&LDSH[ab2 + 4];
            f32x4 c = MFMA16(a1v.v, w1r0, ZERO4);
            c = MFMA16(a2v.v, w1r1, c);
            #pragma unroll
            for (int r = 0; r < 4; r++)
                LDSH[(q * 4 + r) * A1S + p * 16 + col] =
                    f2h(fmaxf(c[r] + b1v, 0.f));
        }
    }
    __syncthreads();

    // ---- 3. conv2 (32x32x16, half-fold): wave wid owns cells {wid, wid+2, ...}
    {
        h8 W2r[9];
        #pragma unroll
        for (int t = 0; t < 9; t++)
            W2r[t] = ((const h8*)w2f)[t * 64 + lane];
        const int m32 = lane & 31, kh = lane >> 5;
        const int samp = lane & 15, half = (lane >> 4) & 1;
        const float b2v = b2[m32];
        const unsigned short* Ab = LDSH + samp * A1S + kh * 8;
        const unsigned short* Zp = LDSH + ZSH + kh * 8;

        u32x4 pk0, pk1, pk2, pk3, pk4;
        __builtin_amdgcn_s_setprio(1);
        {
            int c = wid;         pk0 = conv2_cell(Ab, Zp, W2r, b2v, c / 3, c % 3, half);
        }
        {
            int c = wid + 2;     pk1 = conv2_cell(Ab, Zp, W2r, b2v, c / 3, c % 3, half);
        }
        {
            int c = wid + 4;     pk2 = conv2_cell(Ab, Zp, W2r, b2v, c / 3, c % 3, half);
        }
        {
            int c = wid + 6;     pk3 = conv2_cell(Ab, Zp, W2r, b2v, c / 3, c % 3, half);
        }
        if (wid == 0) {
            pk4 = conv2_cell(Ab, Zp, W2r, b2v, 2, 2, half);
        }
        __builtin_amdgcn_s_setprio(0);
        __syncthreads();   // all A1 reads done before A2 overlays
        #pragma unroll
        for (int rr = 0; rr < 8; rr++) {
            int ss = (rr & 3) + 8 * (rr >> 2) + 4 * kh;   // sample row 0..15
            int rb = ss * A2S + m32;
            LDSH[rb + (wid + 0) * 32] = (unsigned short)(pk0[rr >> 1] >> ((rr & 1) * 16));
            LDSH[rb + (wid + 2) * 32] = (unsigned short)(pk1[rr >> 1] >> ((rr & 1) * 16));
            LDSH[rb + (wid + 4) * 32] = (unsigned short)(pk2[rr >> 1] >> ((rr & 1) * 16));
            LDSH[rb + (wid + 6) * 32] = (unsigned short)(pk3[rr >> 1] >> ((rr & 1) * 16));
        }
        if (wid == 0) {
            #pragma unroll
            for (int rr = 0; rr < 8; rr++) {
                int ss = (rr & 3) + 8 * (rr >> 2) + 4 * kh;
                LDSH[ss * A2S + 8 * 32 + m32] =
                    (unsigned short)(pk4[rr >> 1] >> ((rr & 1) * 16));
            }
        }
    }
    __syncthreads();

    // ---- 4. conv3 -> registers (otp = wid) ----
    f32x4 c3a[9], c3b[9];
    {
        const int otp = wid;
        const int sA2 = col * A2S;
        h8 W3r[18];
        #pragma unroll
        for (int f = 0; f < 18; f++)
            W3r[f] = ((const h8*)w3f)[(otp * 18 + f) * 64 + lane];
        __builtin_amdgcn_s_setprio(1);
        #pragma unroll
        for (int p = 0; p < 9; p++) {
            const int y = p / 3, x = p % 3;
            f32x4 acc0 = ZERO4, acc1 = ZERO4;
            #pragma unroll
            for (int t = 0; t < 9; t++) {
                const int sy = y + t / 3 - 1, sx = x + t % 3 - 1;
                if (sy < 0 || sy >= 3 || sx < 0 || sx >= 3) continue;
                h8 a = *(const h8*)&LDSH[sA2 + (sy * 3 + sx) * 32 + q * 8];
                acc0 = MFMA16(a, W3r[t * 2 + 0], acc0);
                acc1 = MFMA16(a, W3r[t * 2 + 1], acc1);
            }
            c3a[p] = acc0; c3b[p] = acc1;
        }
        __builtin_amdgcn_s_setprio(0);
    }
    __syncthreads();   // all A2 reads done before FT overlays region

    // ---- 5. write FT [p][oc] + quantum + zero tail cols 584..615 ----
    {
        const int otp = wid;
        float b3v0 = b3[(otp * 2 + 0) * 16 + col];
        float b3v1 = b3[(otp * 2 + 1) * 16 + col];
        int oc0 = (otp * 2 + 0) * 16 + col, oc1 = (otp * 2 + 1) * 16 + col;
        #pragma unroll
        for (int p = 0; p < 9; p++)
            #pragma unroll
            for (int r = 0; r < 4; r++) {
                int row = q * 4 + r;
                LDSH[row * FTS + p * 64 + oc0] = f2h(fmaxf(c3a[p][r] + b3v0, 0.f));
                LDSH[row * FTS + p * 64 + oc1] = f2h(fmaxf(c3b[p][r] + b3v1, 0.f));
            }
        {
            int ss = tid >> 3, qq = tid & 7;
            LDSH[ss * FTS + 576 + qq] = f2h(qv0);
        }
        for (int e = tid; e < 512; e += 128)
            LDSH[(e >> 5) * FTS + 584 + (e & 31)] = 0;
    }
    __syncthreads();

    // ---- 6. heads L1: K=608 (19 kk), wave does nt-tiles wid*6..+5 ----
    {
        f32x4 acc[6];
        #pragma unroll
        for (int nt = 0; nt < 6; nt++) acc[nt] = ZERO4;
        const h8* wp1 = (const h8*)w1hd;
        const int ntb = wid * 6;
        __builtin_amdgcn_s_setprio(1);
        for (int kk = 0; kk < 19; kk++) {
            h8 a = *(const h8*)&LDSH[col * FTS + kk * 32 + q * 8];
            #pragma unroll
            for (int nt = 0; nt < 6; nt++) {
                h8 b = wp1[(kk * 12 + ntb + nt) * 64 + lane];
                acc[nt] = MFMA16(a, b, acc[nt]);
            }
        }
        __builtin_amdgcn_s_setprio(0);
        #pragma unroll
        for (int nt = 0; nt < 6; nt++) {
            int ntg = ntb + nt;
            float bv = (ntg < 8) ? ptb1[ntg * 16 + col] : cfb1[(ntg - 8) * 16 + col];
            #pragma unroll
            for (int r = 0; r < 4; r++)
                Hb[(q * 4 + r) * HSH + ntg * 16 + col] =
                    f2h(fmaxf(acc[nt][r] + bv, 0.f));
        }
    }
    __syncthreads();

    // ---- 7. heads L2: wave does nt-tiles {wid*2, wid*2+1}; output to dead
    //      FT region (base 0, stride HSH) -> no pre-write barrier ----
    {
        f32x4 acc2[2];
        acc2[0] = ZERO4; acc2[1] = ZERO4;
        const h8* wp2 = (const h8*)w2hd;
        const int ntb2 = wid * 2;
        #pragma unroll
        for (int kk = 0; kk < 4; kk++) {
            h8 a = *(const h8*)&Hb[col * HSH + kk * 32 + q * 8];
            #pragma unroll
            for (int i = 0; i < 2; i++) {
                h8 b = wp2[(kk * 4 + ntb2 + i) * 64 + lane];
                acc2[i] = MFMA16(a, b, acc2[i]);
            }
        }
        #pragma unroll
        for (int i = 0; i < 2; i++) {
            float bv2 = ptb2[(ntb2 + i) * 16 + col];
            #pragma unroll
            for (int r = 0; r < 4; r++)
                LDSH[(q * 4 + r) * HSH + (ntb2 + i) * 16 + col] =
                    f2h(fmaxf(acc2[i][r] + bv2, 0.f));
        }
    }
    __syncthreads();

    // ---- 8. heads L3 + epilogue: wave 0 ----
    if (wid == 0) {
        f32x4 a3 = ZERO4;
        #pragma unroll
        for (int kk = 0; kk < 4; kk++) {
            // kk 0,1: pt-L2 output (FT region); kk 2,3: cf-L1 output (Hb)
            h8 a = (kk < 2)
                ? *(const h8*)&LDSH[col * HSH + kk * 32 + q * 8]
                : *(const h8*)&Hb[col * HSH + kk * 32 + 64 + q * 8];
            h8 b = ((const h8*)w3hd)[kk * 64 + lane];
            a3 = MFMA16(a, b, a3);
        }
        if (col < 3) {
            float bv = (col < 2) ? ptb3[col] : cfb2[0];
            #pragma unroll
            for (int r = 0; r < 4; r++)
                O[(q * 4 + r) * 4 + col] = a3[r] + bv;
        }
        if (lane < 16) {
            float l0 = O[lane * 4 + 0], l1 = O[lane * 4 + 1], l2 = O[lane * 4 + 2];
            float m = fmaxf(l0, l1);
            float e0 = expf(l0 - m), e1 = expf(l1 - m);
            float inv = 1.f / (e0 + e1);
            float* op = out + (gg0 + lane) * 3;
            op[0] = e0 * inv;
            op[1] = e1 * inv;
            op[2] = 1.f / (1.f + expf(-l2));
        }
    }
}

extern "C" void kernel_launch(void* const* d_in, const int* in_sizes, int n_in,
                              void* d_out, int out_size, void* d_ws, size_t ws_size,
                              hipStream_t stream) {
    const float* board = (const float*)d_in[0];
    const float* c1w  = (const float*)d_in[2];
    const float* c1b  = (const float*)d_in[3];
    const float* c2w  = (const float*)d_in[4];
    const float* c2b  = (const float*)d_in[5];
    const float* c3w  = (const float*)d_in[6];
    const float* c3b  = (const float*)d_in[7];
    const float* qp   = (const float*)d_in[8];
    const float* ptw1 = (const float*)d_in[9];
    const float* ptb1 = (const float*)d_in[10];
    const float* ptw2 = (const float*)d_in[11];
    const float* ptb2 = (const float*)d_in[12];
    const float* ptw3 = (const float*)d_in[13];
    const float* ptb3 = (const float*)d_in[14];
    const float* cfw1 = (const float*)d_in[15];
    const float* cfb1 = (const float*)d_in[16];
    const float* cfw2 = (const float*)d_in[17];
    const float* cfb2 = (const float*)d_in[18];
    float* out = (float*)d_out;

    int Btot = in_sizes[0] / 108;          // 65536

    unsigned short* w1f   = (unsigned short*)d_ws;
    unsigned short* w2f   = (unsigned short*)((char*)d_ws + 2048);
    unsigned short* w3f   = (unsigned short*)((char*)d_ws + 20480);
    unsigned short* w1hd  = (unsigned short*)((char*)d_ws + 57344);
    unsigned short* w2hd  = (unsigned short*)((char*)d_ws + 290816);
    unsigned short* w3hd  = (unsigned short*)((char*)d_ws + 307200);

    hipLaunchKernelGGL(k_prep, dim3(256), dim3(256), 0, stream,
                       c1w, c2w, c3w, ptw1, cfw1, ptw2, ptw3, cfw2,
                       w1f, w2f, w3f, w1hd, w2hd, w3hd);
    hipLaunchKernelGGL(k_fused, dim3(Btot / 16), dim3(128), 0, stream,
                       board, c1b, c2b, c3b, qp, w1f, w2f, w3f,
                       w1hd, w2hd, w3hd, ptb1, ptb2, ptb3, cfb1, cfb2, out);
}